// Round 15
// baseline (149.716 us; speedup 1.0000x reference)
//
#include <hip/hip_runtime.h>
#include <hip/hip_bf16.h>

#define IN_DIM 512
#define OUT_DIM 512

typedef unsigned short u16;
typedef __attribute__((ext_vector_type(4))) float f32x4;
typedef __attribute__((ext_vector_type(8))) __bf16 bf16x8;

// Direct global->LDS DMA, 16B per lane. LDS dest is wave-uniform base + lane*16.
#define GLD16(gp, lp) __builtin_amdgcn_global_load_lds(                       \
    (const __attribute__((address_space(1))) void*)(gp),                      \
    (__attribute__((address_space(3))) void*)(lp), 16, 0, 0)

#define VMCNT(n) asm volatile("s_waitcnt vmcnt(" #n ")" ::: "memory")

__device__ __forceinline__ float softplus_f(float r) {
    return (r > 15.0f) ? r : log1pf(expf(r));
}

// ---------------------------------------------------------------------------
// Kernel 1: fold w = w_mu + softplus(w_rho)*w_eps -> bf16 [OUT][IN] (K-major),
//           b = b_mu + softplus(b_rho)*b_eps -> f32 [OUT], into workspace.
// ---------------------------------------------------------------------------
__global__ void prep_kernel(const float* __restrict__ wmu, const float* __restrict__ wrho,
                            const float* __restrict__ weps, const float* __restrict__ bmu,
                            const float* __restrict__ brho, const float* __restrict__ beps,
                            u16* __restrict__ wbf, float* __restrict__ bias) {
    int gid = blockIdx.x * 256 + threadIdx.x;
    int i4 = gid * 4;
    const float4 mu  = *(const float4*)(wmu + i4);
    const float4 rho = *(const float4*)(wrho + i4);
    const float4 ep  = *(const float4*)(weps + i4);
    union { __bf16 h[4]; uint2 u; } pk;
    pk.h[0] = (__bf16)(mu.x + softplus_f(rho.x) * ep.x);
    pk.h[1] = (__bf16)(mu.y + softplus_f(rho.y) * ep.y);
    pk.h[2] = (__bf16)(mu.z + softplus_f(rho.z) * ep.z);
    pk.h[3] = (__bf16)(mu.w + softplus_f(rho.w) * ep.w);
    *(uint2*)(wbf + i4) = pk.u;
    if (gid < OUT_DIM) {
        bias[gid] = bmu[gid] + softplus_f(brho[gid]) * beps[gid];
    }
}

// ---------------------------------------------------------------------------
// Kernel 2: y = x @ w^T + b, fused dropout.
// 16-PHASE COUNTED-VMCNT PIPELINE (T3+T4 port), f32-A fused (no cvt pass).
//
// Block 256M x 128N, 512 thr = 8 waves (4M x 2N), wave 64x64 (R13-verified
// acc layout + epilogue). K=512 as 8 K-tiles of 64, each split into two
// 32-k halves -> 16 (kt,kk) pairs = 16 phases.
//
// LDS ring: A slots [kt&1][kk] f32 [256][32] (4 x 32 KB) +
//           B slots [kt&1][kk] u16 [128][32] (4 x 8 KB)  = 160 KB, 1 blk/CU.
//
// Phase p (0..15): stage pair p+3 (4+1 GLD16) | 12 swizzled ds_read_b128 +
//   cvt | s_barrier | setprio(1) 16 MFMA setprio(0) | vmcnt(10) | s_barrier.
// vmcnt(10) keeps pairs p+2,p+3 (10 loads) in flight -> pair p+1 landed.
// NEVER drains to 0 until the tail (p=13: 5, p=14: 0). Raw s_barrier keeps
// the counted waits alive (no __syncthreads vmcnt(0) drain).
//
// Slot safety: stage pair p+3 has kk = !(current kk) -> always a different
// slot than the one being read; its previous occupant (pair p-1) was freed
// at the closing barrier of phase p-1, strictly before this issue.
//
// Swizzles (R5-measured, conflict-free): A read p=(2lk+j)^(l15&7); B read
// p=lk^((l15>>1)&3); sources pre-permuted per-lane, LDS dest linear (rule 21).
// ---------------------------------------------------------------------------
__global__ __launch_bounds__(512, 2) void bayes_gemm_16p(
    const float* __restrict__ x, const float* __restrict__ du,
    const u16* __restrict__ wbf, const float* __restrict__ bias,
    float* __restrict__ out)
{
    __shared__ float lA[2][2][256 * 32];   // 128 KB
    __shared__ u16   lB[2][2][128 * 32];   //  32 KB

    const int raw   = blockIdx.x;
    const int lid   = (raw & 7) * 128 + (raw >> 3);   // 1024 % 8 == 0 -> bijective
    const int mband = lid >> 2;      // 0..255 : 256-row band
    const int nband = lid & 3;       // 0..3   : 128-col band (4 sibs per XCD chunk)

    const int tid  = threadIdx.x;
    const int lane = tid & 63;
    const int wv   = tid >> 6;       // 0..7
    const int wm   = wv >> 1;        // 0..3
    const int wn   = wv & 1;         // 0..1
    const int l15  = lane & 15;
    const int lk   = lane >> 4;      // 0..3

    const int row0 = mband * 256;
    const int colb = nband * 128;

    // ---- A staging: half = [256 rows][32 f32], 8 chunks/row; 4 GLD16/thread.
    // load j: row = j*64 + (t>>3), chunk p = t&7; source g = p ^ (row&7)
    //       = (t&7) ^ ((t>>3)&7)  (j*64 == 0 mod 8).
    const int ag  = ((tid & 7) ^ ((tid >> 3) & 7)) * 4;          // f32 col
    const float* gA = x + (size_t)(row0 + (tid >> 3)) * IN_DIM + ag;
    const int alo = (tid >> 3) * 32 + (tid & 7) * 4;             // f32 idx

    // ---- B staging: half = [128 rows][32 u16], 4 chunks/row; 1 GLD16/thread.
    // row = t>>2, chunk p = t&3; source g = p ^ ((row>>1)&3) = (t&3)^((t>>3)&3).
    const int bg  = ((tid & 3) ^ ((tid >> 3) & 3)) * 8;          // u16 col
    const u16* gB = wbf + (size_t)(colb + (tid >> 2)) * IN_DIM + bg;
    const int blo = (tid >> 2) * 32 + (tid & 3) * 8;             // u16 idx

    f32x4 acc[4][4] = {};   // [m][n]

    auto stage_pair = [&](int rp) {          // rp = read-phase index 0..15
        const int kt = rp >> 1, kk = rp & 1;
        const int koff = kt * 64 + kk * 32;  // element offset (f32 for A, u16 for B)
        float* la = &lA[kt & 1][kk][0];
#pragma unroll
        for (int j = 0; j < 4; ++j)
            GLD16(gA + (size_t)(j * 64) * IN_DIM + koff, la + j * 2048 + alo);
        GLD16(gB + koff, &lB[kt & 1][kk][blo]);
    };

    // ---- prologue: pairs 0,1,2 in flight (15 loads); land pair 0.
    stage_pair(0);
    stage_pair(1);
    stage_pair(2);
    VMCNT(10);
    __builtin_amdgcn_s_barrier();

#pragma unroll
    for (int p = 0; p < 16; ++p) {
        const int kt = p >> 1, kk = p & 1, d = kt & 1;
        if (p + 3 < 16) stage_pair(p + 3);   // always a different (kk) slot

        // ---- ds_reads + cvt (pre-barrier region)
        bf16x8 bfr[4];
#pragma unroll
        for (int n = 0; n < 4; ++n) {
            int c  = wn * 64 + n * 16 + l15;
            int pc = lk ^ ((l15 >> 1) & 3);
            bfr[n] = *(const bf16x8*)&lB[d][kk][c * 32 + pc * 8];
        }
        bf16x8 afr[4];
#pragma unroll
        for (int m = 0; m < 4; ++m) {
            int r  = wm * 64 + m * 16 + l15;
            int p0 = (2 * lk)     ^ (l15 & 7);
            int p1 = (2 * lk + 1) ^ (l15 & 7);
            float4 a0 = *(const float4*)&lA[d][kk][r * 32 + p0 * 4];
            float4 a1 = *(const float4*)&lA[d][kk][r * 32 + p1 * 4];
            bf16x8 v;
            v[0] = (__bf16)a0.x; v[1] = (__bf16)a0.y;
            v[2] = (__bf16)a0.z; v[3] = (__bf16)a0.w;
            v[4] = (__bf16)a1.x; v[5] = (__bf16)a1.y;
            v[6] = (__bf16)a1.z; v[7] = (__bf16)a1.w;
            afr[m] = v;
        }

        __builtin_amdgcn_s_barrier();        // role-split barrier (no drain)

        __builtin_amdgcn_s_setprio(1);
#pragma unroll
        for (int m = 0; m < 4; ++m)
#pragma unroll
            for (int n = 0; n < 4; ++n)
                acc[m][n] = __builtin_amdgcn_mfma_f32_16x16x32_bf16(
                    bfr[n], afr[m], acc[m][n], 0, 0, 0);
        __builtin_amdgcn_s_setprio(0);

        // ---- counted drain before the closing barrier: pair p+1 must land,
        // pairs p+2 and p+3 (10 loads) stay in flight.
        if (p < 13)       { VMCNT(10); }
        else if (p == 13) { VMCNT(5); }
        else if (p == 14) { VMCNT(0); }      // tail drain (epilogue next)
        __builtin_amdgcn_s_barrier();
    }

    // ---- epilogue: bias + inverted dropout, dwordx4 (R13-verified indices)
#pragma unroll
    for (int m = 0; m < 4; ++m) {
#pragma unroll
        for (int n = 0; n < 4; ++n) {
            const int colB = colb + wn * 64 + n * 16 + lk * 4;
            const float4 b4 = *(const float4*)(bias + colB);
            size_t off = (size_t)(row0 + wm * 64 + m * 16 + l15) * OUT_DIM + colB;
            const float4 u4 = *(const float4*)(du + off);
            float4 o;
            o.x = (acc[m][n][0] + b4.x) * ((u4.x >= 0.2f) ? 1.25f : 0.0f);
            o.y = (acc[m][n][1] + b4.y) * ((u4.y >= 0.2f) ? 1.25f : 0.0f);
            o.z = (acc[m][n][2] + b4.z) * ((u4.z >= 0.2f) ? 1.25f : 0.0f);
            o.w = (acc[m][n][3] + b4.w) * ((u4.w >= 0.2f) ? 1.25f : 0.0f);
            *(float4*)(out + off) = o;
        }
    }
}

extern "C" void kernel_launch(void* const* d_in, const int* in_sizes, int n_in,
                              void* d_out, int out_size, void* d_ws, size_t ws_size,
                              hipStream_t stream) {
    const float* x    = (const float*)d_in[0];
    const float* wmu  = (const float*)d_in[1];
    const float* wrho = (const float*)d_in[2];
    const float* bmu  = (const float*)d_in[3];
    const float* brho = (const float*)d_in[4];
    const float* weps = (const float*)d_in[5];
    const float* beps = (const float*)d_in[6];
    const float* du   = (const float*)d_in[7];
    float* out = (float*)d_out;

    u16*   wbf  = (u16*)d_ws;
    float* bias = (float*)((char*)d_ws + OUT_DIM * IN_DIM * sizeof(u16));

    prep_kernel<<<256, 256, 0, stream>>>(wmu, wrho, weps, bmu, brho, beps, wbf, bias);

    // 256 M-bands x 4 N-bands, 1 block/CU (160 KB LDS), 4 generations
    bayes_gemm_16p<<<1024, 512, 0, stream>>>(x, du, wbf, bias, out);
}

// Round 16
// 142.999 us; speedup vs baseline: 1.0470x; 1.0470x over previous
//
#include <hip/hip_runtime.h>
#include <hip/hip_bf16.h>

#define IN_DIM 512
#define OUT_DIM 512

typedef unsigned short u16;
typedef __attribute__((ext_vector_type(4))) float f32x4;
typedef __attribute__((ext_vector_type(8))) __bf16 bf16x8;

// Direct global->LDS DMA, 16B per lane. LDS dest is wave-uniform base + lane*16.
#define GLD16(gp, lp) __builtin_amdgcn_global_load_lds(                       \
    (const __attribute__((address_space(1))) void*)(gp),                      \
    (__attribute__((address_space(3))) void*)(lp), 16, 0, 0)

__device__ __forceinline__ float softplus_f(float r) {
    return (r > 15.0f) ? r : log1pf(expf(r));
}

// ---------------------------------------------------------------------------
// Kernel 1: fold w = w_mu + softplus(w_rho)*w_eps -> bf16 [OUT][IN] (K-major),
//           b = b_mu + softplus(b_rho)*b_eps -> f32 [OUT], into workspace.
// ---------------------------------------------------------------------------
__global__ void prep_kernel(const float* __restrict__ wmu, const float* __restrict__ wrho,
                            const float* __restrict__ weps, const float* __restrict__ bmu,
                            const float* __restrict__ brho, const float* __restrict__ beps,
                            u16* __restrict__ wbf, float* __restrict__ bias) {
    int gid = blockIdx.x * 256 + threadIdx.x;
    int i4 = gid * 4;
    const float4 mu  = *(const float4*)(wmu + i4);
    const float4 rho = *(const float4*)(wrho + i4);
    const float4 ep  = *(const float4*)(weps + i4);
    union { __bf16 h[4]; uint2 u; } pk;
    pk.h[0] = (__bf16)(mu.x + softplus_f(rho.x) * ep.x);
    pk.h[1] = (__bf16)(mu.y + softplus_f(rho.y) * ep.y);
    pk.h[2] = (__bf16)(mu.z + softplus_f(rho.z) * ep.z);
    pk.h[3] = (__bf16)(mu.w + softplus_f(rho.w) * ep.w);
    *(uint2*)(wbf + i4) = pk.u;
    if (gid < OUT_DIM) {
        bias[gid] = bmu[gid] + softplus_f(brho[gid]) * beps[gid];
    }
}

// ---------------------------------------------------------------------------
// Kernel 2: y = x @ w^T + b, fused dropout, SELF-CONVERTING (no serial cvt).
//
// Each block first converts ITS OWN 256-row x-band f32->bf16 into xb
// (coalesced float4x2 -> uint4), vmcnt(0)+syncthreads, then runs the
// R14-verified GEMM core reading xb: the fresh lines sit in the local XCD's
// L2, so A-staging DMA gets L2-service instead of L3. A block reads only
// rows it wrote -> no cross-block sync needed. The 2 N-siblings of a band
// (nband 0/1, XCD-adjacent lids) redundantly convert the same band: benign
// same-value writes; the sibling's x-f32 read hits L2/L3.
//
// GEMM core (R14, measured 107us / absmax 0.0625): block 256M x 256N,
// 1024 thr = 16 waves (4M x 4N), wave 64x64, BK=64 as 2 k-halves, 8 steps,
// double-buffered 128 KB LDS, rule-21 chunk swizzle (2-way max):
//   stored chunk p holds global chunk g = p ^ (row&3) ^ ((row>>2)&3)
//   read chunk ap = lk ^ (l15&3) ^ ((l15>>2)&3)
// ---------------------------------------------------------------------------
__global__ __launch_bounds__(1024, 4) void bayes_gemm_fused(
    const float* __restrict__ x, u16* __restrict__ xb,
    const float* __restrict__ du, const u16* __restrict__ wbf,
    const float* __restrict__ bias, float* __restrict__ out)
{
    __shared__ u16 lA[2][2][256 * 32];   // [buf][k-half] : 64 KB
    __shared__ u16 lB[2][2][256 * 32];   // 64 KB

    const int raw   = blockIdx.x;
    const int lid   = (raw & 7) * 64 + (raw >> 3);   // 512 % 8 == 0 -> bijective
    const int mband = lid >> 1;      // 0..255 : 256-row band
    const int nband = lid & 1;       // 0..1   : 256-col band (sibling same XCD)

    const int tid  = threadIdx.x;
    const int lane = tid & 63;
    const int wv   = tid >> 6;       // 0..15
    const int wm   = wv >> 2;        // 0..3
    const int wn   = wv & 3;         // 0..3
    const int l15  = lane & 15;
    const int lk   = lane >> 4;      // 0..3

    const int row0 = mband * 256;
    const int colb = nband * 256;

    // ---- phase 0: self-convert x rows [row0, row0+256) -> xb, coalesced.
    // 131072 f32 per band: 16 iters x 1024 thr x 8 f32 (2 float4 -> 1 uint4).
    {
        const float* xs = x + (size_t)row0 * IN_DIM;
        u16* xd = xb + (size_t)row0 * IN_DIM;
#pragma unroll
        for (int i = 0; i < 16; ++i) {
            const size_t idx = (size_t)i * 8192 + tid * 8;
            const float4 a0 = *(const float4*)(xs + idx);
            const float4 a1 = *(const float4*)(xs + idx + 4);
            union { __bf16 h[8]; uint4 u; } pk;
            pk.h[0] = (__bf16)a0.x; pk.h[1] = (__bf16)a0.y;
            pk.h[2] = (__bf16)a0.z; pk.h[3] = (__bf16)a0.w;
            pk.h[4] = (__bf16)a1.x; pk.h[5] = (__bf16)a1.y;
            pk.h[6] = (__bf16)a1.z; pk.h[7] = (__bf16)a1.w;
            *(uint4*)(xd + idx) = pk.u;
        }
    }
    asm volatile("s_waitcnt vmcnt(0)" ::: "memory");   // stores retired to L2
    __syncthreads();

    // ---- staging geometry (linear LDS dest, source chunk pre-permuted)
    // thread t -> row t>>2, chunk p = t&3; g = p ^ (row&3) ^ ((row>>2)&3)
    //           = (t&3) ^ ((t>>2)&3) ^ ((t>>4)&3).
    const int sg  = ((tid & 3) ^ ((tid >> 2) & 3) ^ ((tid >> 4) & 3)) * 8;  // u16
    const int trc = tid >> 2;                        // 0..255
    const u16* gA = xb  + (size_t)(row0 + trc) * IN_DIM + sg;
    const u16* gB = wbf + (size_t)(colb + trc) * IN_DIM + sg;
    const int lso = trc * 32 + (tid & 3) * 8;        // u16 idx within a half

    // fragment-read chunk permutation
    const int ap = (lk ^ (l15 & 3) ^ ((l15 >> 2) & 3)) * 8;

    f32x4 acc[4][4] = {};   // [m][n]

    auto stage = [&](int t, int buf) {
        GLD16(gA + t * 64,      &lA[buf][0][lso]);   // A k-half 0
        GLD16(gA + t * 64 + 32, &lA[buf][1][lso]);   // A k-half 1
        GLD16(gB + t * 64,      &lB[buf][0][lso]);   // B k-half 0
        GLD16(gB + t * 64 + 32, &lB[buf][1][lso]);   // B k-half 1
    };

    // ---- prologue
    stage(0, 0);
    __syncthreads();

#pragma unroll
    for (int t = 0; t < 8; ++t) {
        const int buf = t & 1;
        if (t + 1 < 8) stage(t + 1, buf ^ 1);   // async DMA, hidden under fat step

#pragma unroll
        for (int kk = 0; kk < 2; ++kk) {
            bf16x8 bfr[4], afr[4];
#pragma unroll
            for (int n = 0; n < 4; ++n) {
                int c = wn * 64 + n * 16 + l15;
                bfr[n] = *(const bf16x8*)&lB[buf][kk][c * 32 + ap];
            }
#pragma unroll
            for (int m = 0; m < 4; ++m) {
                int r = wm * 64 + m * 16 + l15;
                afr[m] = *(const bf16x8*)&lA[buf][kk][r * 32 + ap];
            }
#pragma unroll
            for (int m = 0; m < 4; ++m)
#pragma unroll
                for (int n = 0; n < 4; ++n)
                    acc[m][n] = __builtin_amdgcn_mfma_f32_16x16x32_bf16(
                        bfr[n], afr[m], acc[m][n], 0, 0, 0);
        }

        __syncthreads();
    }

    // ---- epilogue: bias + inverted dropout, dwordx4 throughout
#pragma unroll
    for (int m = 0; m < 4; ++m) {
#pragma unroll
        for (int n = 0; n < 4; ++n) {
            const int colB = colb + wn * 64 + n * 16 + lk * 4;
            const float4 b4 = *(const float4*)(bias + colB);
            size_t off = (size_t)(row0 + wm * 64 + m * 16 + l15) * OUT_DIM + colB;
            const float4 u4 = *(const float4*)(du + off);
            float4 o;
            o.x = (acc[m][n][0] + b4.x) * ((u4.x >= 0.2f) ? 1.25f : 0.0f);
            o.y = (acc[m][n][1] + b4.y) * ((u4.y >= 0.2f) ? 1.25f : 0.0f);
            o.z = (acc[m][n][2] + b4.z) * ((u4.z >= 0.2f) ? 1.25f : 0.0f);
            o.w = (acc[m][n][3] + b4.w) * ((u4.w >= 0.2f) ? 1.25f : 0.0f);
            *(float4*)(out + off) = o;
        }
    }
}

// ---------------------------------------------------------------------------
// Fallback (ws too small for xb): R5-style fused f32-A staged kernel.
// ---------------------------------------------------------------------------
__global__ __launch_bounds__(256, 3) void bayes_gemm_f32a(
    const float* __restrict__ x, const float* __restrict__ du,
    const u16* __restrict__ wbf, const float* __restrict__ bias,
    float* __restrict__ out)
{
    __shared__ float lAf[2][128 * 32];
    __shared__ u16   lBf[2][128 * 32];

    const int raw   = blockIdx.x;
    const int lid   = (raw & 7) * 256 + (raw >> 3);
    const int mband = lid >> 2;
    const int nband = lid & 3;

    const int tid  = threadIdx.x;
    const int lane = tid & 63;
    const int wv   = tid >> 6;
    const int wm   = wv >> 1;
    const int wn   = wv & 1;
    const int l15  = lane & 15;
    const int lk   = lane >> 4;

    const int row0 = mband * 128;
    const int colb = nband * 128;

    const int arow  = wv * 8 + (lane >> 3);
    const int acswz = ((lane & 7) ^ (lane >> 3)) * 4;
    const float* gA = x + (size_t)(row0 + arow) * IN_DIM + acswz;
    const int brow  = wv * 16 + (lane >> 2);
    const int bcswz = ((lane & 3) ^ ((lane >> 3) & 3)) * 8;
    const u16* gB = wbf + (size_t)(colb + brow) * IN_DIM + bcswz;

    f32x4 acc[4][4] = {};

    auto stage = [&](int t, int buf) {
#pragma unroll
        for (int i = 0; i < 4; ++i)
            GLD16(gA + (size_t)i * 32 * IN_DIM + t * 32, &lAf[buf][i * 1024 + wv * 256]);
#pragma unroll
        for (int i = 0; i < 2; ++i)
            GLD16(gB + (size_t)i * 64 * IN_DIM + t * 32, &lBf[buf][i * 2048 + wv * 512]);
    };

    stage(0, 0);
    __syncthreads();

#pragma unroll
    for (int t = 0; t < 16; ++t) {
        const int buf = t & 1;
        if (t + 1 < 16) stage(t + 1, buf ^ 1);

        bf16x8 wf[4];
#pragma unroll
        for (int n = 0; n < 4; ++n) {
            int r = wn * 64 + n * 16 + l15;
            int p = lk ^ ((l15 >> 1) & 3);
            wf[n] = *(const bf16x8*)&lBf[buf][r * 32 + p * 8];
        }
#pragma unroll
        for (int m = 0; m < 4; ++m) {
            int r  = wm * 64 + m * 16 + l15;
            int p0 = (2 * lk)     ^ (l15 & 7);
            int p1 = (2 * lk + 1) ^ (l15 & 7);
            float4 a0 = *(const float4*)&lAf[buf][r * 32 + p0 * 4];
            float4 a1 = *(const float4*)&lAf[buf][r * 32 + p1 * 4];
            bf16x8 xf;
            xf[0] = (__bf16)a0.x; xf[1] = (__bf16)a0.y;
            xf[2] = (__bf16)a0.z; xf[3] = (__bf16)a0.w;
            xf[4] = (__bf16)a1.x; xf[5] = (__bf16)a1.y;
            xf[6] = (__bf16)a1.z; xf[7] = (__bf16)a1.w;
#pragma unroll
            for (int n = 0; n < 4; ++n)
                acc[m][n] = __builtin_amdgcn_mfma_f32_16x16x32_bf16(
                    wf[n], xf, acc[m][n], 0, 0, 0);
        }
        __syncthreads();
    }

#pragma unroll
    for (int m = 0; m < 4; ++m) {
#pragma unroll
        for (int n = 0; n < 4; ++n) {
            const int colB = colb + wn * 64 + n * 16 + lk * 4;
            const float4 b4 = *(const float4*)(bias + colB);
            size_t off = (size_t)(row0 + wm * 64 + m * 16 + l15) * OUT_DIM + colB;
            const float4 u4 = *(const float4*)(du + off);
            float4 o;
            o.x = (acc[m][n][0] + b4.x) * ((u4.x >= 0.2f) ? 1.25f : 0.0f);
            o.y = (acc[m][n][1] + b4.y) * ((u4.y >= 0.2f) ? 1.25f : 0.0f);
            o.z = (acc[m][n][2] + b4.z) * ((u4.z >= 0.2f) ? 1.25f : 0.0f);
            o.w = (acc[m][n][3] + b4.w) * ((u4.w >= 0.2f) ? 1.25f : 0.0f);
            *(float4*)(out + off) = o;
        }
    }
}

extern "C" void kernel_launch(void* const* d_in, const int* in_sizes, int n_in,
                              void* d_out, int out_size, void* d_ws, size_t ws_size,
                              hipStream_t stream) {
    const float* x    = (const float*)d_in[0];
    const float* wmu  = (const float*)d_in[1];
    const float* wrho = (const float*)d_in[2];
    const float* bmu  = (const float*)d_in[3];
    const float* brho = (const float*)d_in[4];
    const float* weps = (const float*)d_in[5];
    const float* beps = (const float*)d_in[6];
    const float* du   = (const float*)d_in[7];
    float* out = (float*)d_out;

    u16*   wbf  = (u16*)d_ws;
    float* bias = (float*)((char*)d_ws + OUT_DIM * IN_DIM * sizeof(u16));
    u16*   xb   = (u16*)((char*)d_ws + (1 << 20));   // x_bf16 at +1 MB

    const size_t need = (1u << 20) + (size_t)65536 * IN_DIM * sizeof(u16);

    prep_kernel<<<256, 256, 0, stream>>>(wmu, wrho, weps, bmu, brho, beps, wbf, bias);

    if (ws_size >= need) {
        // 256 M-bands x 2 N-bands; self-converting fused GEMM
        bayes_gemm_fused<<<512, 1024, 0, stream>>>(x, xb, du, wbf, bias, out);
    } else {
        bayes_gemm_f32a<<<2048, 256, 0, stream>>>(x, du, wbf, bias, out);
    }
}